// Round 20
// baseline (291.915 us; speedup 1.0000x reference)
//
#include <hip/hip_runtime.h>

// Capsule routing, B=64 R=2048 C=32 O=32 I=16, 3 routing iters.
// u_hat never materialized; recomputed per pass. Logit telescoping:
// b1 = u.v1 ; b2 = u.(v1+v2).
//
// R31: 2-rr BATCHED SOFTMAX in phases 1/2 (barrier test; 16 -> 8 barriers).
//   R30 post-mortem: traffic model holds (~5 TB/s L2-level wall; R15/R28/
//   R30 deltas all fit), but phase rates differ: ph0 (no barrier in loop)
//   = 4.3 TB/s vs ph1/2 (barrier/rr) = 2.3 TB/s. Test: batch 2 rr per
//   barrier. Logit pass streams D through regs (discard), ONE barrier per
//   pair, then RECOMPUTE D (2nd MFMA pass, 3.5->7% util, cheap) for the
//   weighted accumulation. Next-pair W loads issued post-barrier fly under
//   recompute MFMAs. Phase 0 / stores / reduce untouched; math identical.
//   Pre-commit: neutral => barrier theory CLOSED (latency floor).
// R30 (kept): fp16 s_part (16 MB); RCH=16, 256 blocks, bound=1.
// R25 (kept): wconv folded into upass<0> (fp32 W read, bg==0 persists Wh).
// R15 (kept): NG=2 b-fusion, 32 b/block; fused reduce_squash.
// R11 baseline: MFMA 16x16x16 per tile; D row=4q+reg, col=lane&15.

#define Bn 64
#define Rn 2048
#define Cn 32
#define On 32
#define In 16
#define RCH 16            // r per block
#define NRC2 (Rn / RCH)   // 128 r-chunks
#define NG 2              // fused b-groups of 32

typedef _Float16 half4v __attribute__((ext_vector_type(4)));
typedef float floatx4 __attribute__((ext_vector_type(4)));

// s_part: [NRC2][64 b][1024 co] fp16 (16 MB)
template <int PHASE>
__global__ __launch_bounds__(512, 1)
void upass(const float* __restrict__ x, const float* __restrict__ Wfp,
           _Float16* __restrict__ Wh, const float* __restrict__ vroute,
           _Float16* __restrict__ s_part) {
    const int tid  = threadIdx.x;
    const int w    = tid >> 6;      // wave 0..7 -> c = 4w..4w+3
    const int lane = tid & 63;
    const int q    = lane >> 4;     // quad
    const int bl   = lane & 15;     // A row / B col / D col

    // XCD swizzle: the 2 bg-blocks of one rc are L and L+8 -> same XCD.
    const int L  = blockIdx.x;                  // [0,256)
    const int bg = (L >> 3) & 1;
    const int rc = (L & 7) | ((L >> 4) << 3);   // [0,128)
    const int b0 = bg * 32;

    // xs[rr][bb 32][20] halfs (pad 16->20: 8B-aligned b64, conflict-free)
    __shared__ __attribute__((aligned(16))) _Float16 xs[RCH * 32 * 20];
    // [buf][sub][q][bl][w] - double-buffered across rr-pairs
    __shared__ __attribute__((aligned(16))) float sums[2][2][2][16][8];

    // ---- v slice -> registers (r-invariant). g=0: b0+bl, g=1: b0+16+bl ----
    floatx4 v00[4], v01[4], v10[4], v11[4];
    if constexpr (PHASE > 0) {
        const float* vb0 = vroute + (size_t)(b0 + bl) * 1024 + 4 * q;
        const float* vb1 = vroute + (size_t)(b0 + 16 + bl) * 1024 + 4 * q;
#pragma unroll
        for (int t = 0; t < 4; ++t) {
            const int co = (w * 4 + t) * 32;
            v00[t] = *(const floatx4*)(vb0 + co);
            v01[t] = *(const floatx4*)(vb0 + co + 16);
            v10[t] = *(const floatx4*)(vb1 + co);
            v11[t] = *(const floatx4*)(vb1 + co + 16);
        }
    }

    // ---- preload x chunk -> fp16 LDS: 16 r x 32 b x 16 i ----
#pragma unroll
    for (int k = 0; k < 4; ++k) {
        const int u  = tid + k * 512;           // [0,2048)
        const int rr = u >> 7, bb = (u >> 2) & 31, iq = u & 3;
        const float4 xv = *(const float4*)(x + (size_t)(b0 + bb) * (Rn * In) +
                                           (size_t)(rc * RCH + rr) * In + iq * 4);
        union { _Float16 h[4]; uint2 u2; } p;
        p.h[0] = (_Float16)xv.x; p.h[1] = (_Float16)xv.y;
        p.h[2] = (_Float16)xv.z; p.h[3] = (_Float16)xv.w;
        *(uint2*)(xs + (rr * 32 + bb) * 20 + iq * 4) = p.u2;
    }
    __syncthreads();

    floatx4 accS0[8], accS1[8];
#pragma unroll
    for (int m = 0; m < 8; ++m) {
        accS0[m] = (floatx4){0.f, 0.f, 0.f, 0.f};
        accS1[m] = (floatx4){0.f, 0.f, 0.f, 0.f};
    }

    // A base: W[r, co = w*128 + m*16 + bl, i = 4q..4q+3]; per-r stride 16384 elems
    const size_t abase = ((size_t)(rc * RCH) * 1024 + w * 128 + bl) * 16 + 4 * q;

    if constexpr (PHASE == 0) {
        for (int rr = 0; rr < RCH; ++rr) {
            // fp32 W read (1KB coalesced segments), in-reg cvt, fp16 persist.
            const size_t rb = abase + (size_t)rr * 16384;
            const float* Wf = Wfp + rb;
            half4v af[8];
#pragma unroll
            for (int m = 0; m < 8; ++m) {
                const float4 t4 = *(const float4*)(Wf + m * 256);
                af[m] = (half4v){(_Float16)t4.x, (_Float16)t4.y,
                                 (_Float16)t4.z, (_Float16)t4.w};
            }
            if (bg == 0) {
                _Float16* whp = Wh + rb;
#pragma unroll
                for (int m = 0; m < 8; ++m) *(half4v*)(whp + m * 256) = af[m];
            }
            const half4v b0v = *(const half4v*)(xs + (rr * 32 + bl) * 20 + 4 * q);
            const half4v b1v = *(const half4v*)(xs + (rr * 32 + 16 + bl) * 20 + 4 * q);
#pragma unroll
            for (int m = 0; m < 8; ++m) {
                accS0[m] = __builtin_amdgcn_mfma_f32_16x16x16f16(af[m], b0v, accS0[m], 0, 0, 0);
                accS1[m] = __builtin_amdgcn_mfma_f32_16x16x16f16(af[m], b1v, accS1[m], 0, 0, 0);
            }
        }
    } else {
        // a0 primed for rr=0
        half4v a0[8], a1[8], a0n[8];
#pragma unroll
        for (int m = 0; m < 8; ++m) a0[m] = *(const half4v*)(Wh + abase + m * 256);

        for (int rr2 = 0; rr2 < RCH; rr2 += 2) {
            const int buf = (rr2 >> 1) & 1;
            // load a1 (rr2+1) + all 4 x-fragments for the pair
            const _Float16* W1 = Wh + abase + (size_t)(rr2 + 1) * 16384;
#pragma unroll
            for (int m = 0; m < 8; ++m) a1[m] = *(const half4v*)(W1 + m * 256);
            const half4v bf0a = *(const half4v*)(xs + (rr2 * 32 + bl) * 20 + 4 * q);
            const half4v bf1a = *(const half4v*)(xs + (rr2 * 32 + 16 + bl) * 20 + 4 * q);
            const half4v bf0b = *(const half4v*)(xs + ((rr2 + 1) * 32 + bl) * 20 + 4 * q);
            const half4v bf1b = *(const half4v*)(xs + ((rr2 + 1) * 32 + 16 + bl) * 20 + 4 * q);

            // ---- logit pass (D streamed, discarded) ----
            float e0a[4], e1a[4], e0b[4], e1b[4];
            float se0a = 0.f, se1a = 0.f, se0b = 0.f, se1b = 0.f;
#pragma unroll
            for (int t = 0; t < 4; ++t) {
                const floatx4 z = (floatx4){0.f, 0.f, 0.f, 0.f};
                floatx4 Dx, Dy;
                // rr2, group0
                Dx = __builtin_amdgcn_mfma_f32_16x16x16f16(a0[2*t],   bf0a, z, 0, 0, 0);
                Dy = __builtin_amdgcn_mfma_f32_16x16x16f16(a0[2*t+1], bf0a, z, 0, 0, 0);
                float lp0 = Dx.x*v00[t].x + Dx.y*v00[t].y + Dx.z*v00[t].z + Dx.w*v00[t].w +
                            Dy.x*v01[t].x + Dy.y*v01[t].y + Dy.z*v01[t].z + Dy.w*v01[t].w;
                // rr2, group1
                Dx = __builtin_amdgcn_mfma_f32_16x16x16f16(a0[2*t],   bf1a, z, 0, 0, 0);
                Dy = __builtin_amdgcn_mfma_f32_16x16x16f16(a0[2*t+1], bf1a, z, 0, 0, 0);
                float lp1 = Dx.x*v10[t].x + Dx.y*v10[t].y + Dx.z*v10[t].z + Dx.w*v10[t].w +
                            Dy.x*v11[t].x + Dy.y*v11[t].y + Dy.z*v11[t].z + Dy.w*v11[t].w;
                // rr2+1, group0
                Dx = __builtin_amdgcn_mfma_f32_16x16x16f16(a1[2*t],   bf0b, z, 0, 0, 0);
                Dy = __builtin_amdgcn_mfma_f32_16x16x16f16(a1[2*t+1], bf0b, z, 0, 0, 0);
                float lp2 = Dx.x*v00[t].x + Dx.y*v00[t].y + Dx.z*v00[t].z + Dx.w*v00[t].w +
                            Dy.x*v01[t].x + Dy.y*v01[t].y + Dy.z*v01[t].z + Dy.w*v01[t].w;
                // rr2+1, group1
                Dx = __builtin_amdgcn_mfma_f32_16x16x16f16(a1[2*t],   bf1b, z, 0, 0, 0);
                Dy = __builtin_amdgcn_mfma_f32_16x16x16f16(a1[2*t+1], bf1b, z, 0, 0, 0);
                float lp3 = Dx.x*v10[t].x + Dx.y*v10[t].y + Dx.z*v10[t].z + Dx.w*v10[t].w +
                            Dy.x*v11[t].x + Dy.y*v11[t].y + Dy.z*v11[t].z + Dy.w*v11[t].w;

                lp0 += __shfl_xor(lp0, 16, 64);  lp0 += __shfl_xor(lp0, 32, 64);
                lp1 += __shfl_xor(lp1, 16, 64);  lp1 += __shfl_xor(lp1, 32, 64);
                lp2 += __shfl_xor(lp2, 16, 64);  lp2 += __shfl_xor(lp2, 32, 64);
                lp3 += __shfl_xor(lp3, 16, 64);  lp3 += __shfl_xor(lp3, 32, 64);
                e0a[t] = __expf(lp0); se0a += e0a[t];   // no max-subtract (|l| small)
                e1a[t] = __expf(lp1); se1a += e1a[t];
                e0b[t] = __expf(lp2); se0b += e0b[t];
                e1b[t] = __expf(lp3); se1b += e1b[t];
            }
            if (lane < 32) {
                sums[buf][0][q][bl][w] = q ? se1a : se0a;
                sums[buf][1][q][bl][w] = q ? se1b : se0b;
            }
            asm volatile("s_waitcnt lgkmcnt(0)" ::: "memory");
            __builtin_amdgcn_s_barrier();
            asm volatile("" ::: "memory");

            // prefetch a0 for next pair NOW; flies under recompute MFMAs
            const int rn = (rr2 + 2 < RCH) ? rr2 + 2 : rr2;
            const _Float16* Wn = Wh + abase + (size_t)rn * 16384;
#pragma unroll
            for (int m = 0; m < 8; ++m) a0n[m] = *(const half4v*)(Wn + m * 256);

            const floatx4 sa0 = *(const floatx4*)(&sums[buf][0][0][bl][0]);
            const floatx4 sa1 = *(const floatx4*)(&sums[buf][0][0][bl][4]);
            const floatx4 sb0 = *(const floatx4*)(&sums[buf][0][1][bl][0]);
            const floatx4 sb1 = *(const floatx4*)(&sums[buf][0][1][bl][4]);
            const floatx4 sc0 = *(const floatx4*)(&sums[buf][1][0][bl][0]);
            const floatx4 sc1 = *(const floatx4*)(&sums[buf][1][0][bl][4]);
            const floatx4 sd0 = *(const floatx4*)(&sums[buf][1][1][bl][0]);
            const floatx4 sd1 = *(const floatx4*)(&sums[buf][1][1][bl][4]);
            const float winv0a = __builtin_amdgcn_rcpf(
                sa0.x+sa0.y+sa0.z+sa0.w + sa1.x+sa1.y+sa1.z+sa1.w);
            const float winv1a = __builtin_amdgcn_rcpf(
                sb0.x+sb0.y+sb0.z+sb0.w + sb1.x+sb1.y+sb1.z+sb1.w);
            const float winv0b = __builtin_amdgcn_rcpf(
                sc0.x+sc0.y+sc0.z+sc0.w + sc1.x+sc1.y+sc1.z+sc1.w);
            const float winv1b = __builtin_amdgcn_rcpf(
                sd0.x+sd0.y+sd0.z+sd0.w + sd1.x+sd1.y+sd1.z+sd1.w);

            // ---- recompute-D pass + weighted accumulate ----
#pragma unroll
            for (int t = 0; t < 4; ++t) {
                const floatx4 z = (floatx4){0.f, 0.f, 0.f, 0.f};
                const float wt0a = e0a[t] * winv0a, wt1a = e1a[t] * winv1a;
                const float wt0b = e0b[t] * winv0b, wt1b = e1b[t] * winv1b;
                floatx4 Dx, Dy;
                Dx = __builtin_amdgcn_mfma_f32_16x16x16f16(a0[2*t],   bf0a, z, 0, 0, 0);
                Dy = __builtin_amdgcn_mfma_f32_16x16x16f16(a0[2*t+1], bf0a, z, 0, 0, 0);
                accS0[2*t] += wt0a * Dx;  accS0[2*t+1] += wt0a * Dy;
                Dx = __builtin_amdgcn_mfma_f32_16x16x16f16(a0[2*t],   bf1a, z, 0, 0, 0);
                Dy = __builtin_amdgcn_mfma_f32_16x16x16f16(a0[2*t+1], bf1a, z, 0, 0, 0);
                accS1[2*t] += wt1a * Dx;  accS1[2*t+1] += wt1a * Dy;
                Dx = __builtin_amdgcn_mfma_f32_16x16x16f16(a1[2*t],   bf0b, z, 0, 0, 0);
                Dy = __builtin_amdgcn_mfma_f32_16x16x16f16(a1[2*t+1], bf0b, z, 0, 0, 0);
                accS0[2*t] += wt0b * Dx;  accS0[2*t+1] += wt0b * Dy;
                Dx = __builtin_amdgcn_mfma_f32_16x16x16f16(a1[2*t],   bf1b, z, 0, 0, 0);
                Dy = __builtin_amdgcn_mfma_f32_16x16x16f16(a1[2*t+1], bf1b, z, 0, 0, 0);
                accS1[2*t] += wt1b * Dx;  accS1[2*t+1] += wt1b * Dy;
            }
#pragma unroll
            for (int m = 0; m < 8; ++m) a0[m] = a0n[m];
        }
    }

    // store fp16 partials: co = w*128 + m*16 + 4q + reg (4 halves = 8B/store)
    const size_t sb = (((size_t)rc * 64 + b0 + bl)) * 1024 + w * 128 + 4 * q;
#pragma unroll
    for (int m = 0; m < 8; ++m) {
        const floatx4 a0v = accS0[m], a1v = accS1[m];
        const half4v h0 = {(_Float16)a0v.x, (_Float16)a0v.y, (_Float16)a0v.z, (_Float16)a0v.w};
        const half4v h1 = {(_Float16)a1v.x, (_Float16)a1v.y, (_Float16)a1v.z, (_Float16)a1v.w};
        *(half4v*)(s_part + sb + m * 16) = h0;
        *(half4v*)(s_part + sb + (size_t)16 * 1024 + m * 16) = h1;
    }
}

// Fused reduce(128 rc-partials fp16, fp32 accumulate) + squash.
// Grid: 64 b x 8 co-octs = 512 blocks; 256 thr = 8 k-groups x 32 half4.
__global__ __launch_bounds__(256)
void reduce_squash(const _Float16* __restrict__ sp, float scale,
                   float* __restrict__ vout, const float* __restrict__ vprev,
                   float* __restrict__ vsum) {
    const int b = blockIdx.x >> 3, oct = blockIdx.x & 7;
    const int t = threadIdx.x;
    const int kg = t >> 5, ci = t & 31;
    const size_t base = (size_t)b * 1024 + (size_t)oct * 128 + (size_t)ci * 4;

    floatx4 acc0 = (floatx4){0.f, 0.f, 0.f, 0.f};
    floatx4 acc1 = (floatx4){0.f, 0.f, 0.f, 0.f};
#pragma unroll
    for (int k = kg * 16; k < kg * 16 + 16; k += 2) {
        const half4v h0 = *(const half4v*)(sp + (size_t)k * 65536 + base);
        const half4v h1 = *(const half4v*)(sp + (size_t)(k + 1) * 65536 + base);
        acc0 += (floatx4){(float)h0.x, (float)h0.y, (float)h0.z, (float)h0.w};
        acc1 += (floatx4){(float)h1.x, (float)h1.y, (float)h1.z, (float)h1.w};
    }
    const floatx4 acc = acc0 + acc1;

    __shared__ __attribute__((aligned(16))) float red[8][128];
    *(floatx4*)(&red[kg][ci * 4]) = acc;
    __syncthreads();

    if (t < 128) {                     // element f = t : c = oct*4 + (t>>5), o = t&31
        float s = 0.f;
#pragma unroll
        for (int g = 0; g < 8; ++g) s += red[g][t];
        s *= scale;
        float n2 = s * s;              // norm over o: lane bits 0..4
        n2 += __shfl_xor(n2, 1, 64);
        n2 += __shfl_xor(n2, 2, 64);
        n2 += __shfl_xor(n2, 4, 64);
        n2 += __shfl_xor(n2, 8, 64);
        n2 += __shfl_xor(n2, 16, 64);
        const float norm = sqrtf(n2);
        const float f = (n2 / (1.f + n2)) / (norm + 1e-8f);
        const float vv = s * f;
        const size_t o = (size_t)b * 1024 + (size_t)oct * 128 + t;
        if (vout) vout[o] = vv;
        if (vsum) vsum[o] = vv + vprev[o];
    }
}

extern "C" void kernel_launch(void* const* d_in, const int* in_sizes, int n_in,
                              void* d_out, int out_size, void* d_ws, size_t ws_size,
                              hipStream_t stream) {
    const float* x = (const float*)d_in[0];   // [64,2048,16]
    const float* W = (const float*)d_in[1];   // [2048,32,32,16]
    float* out = (float*)d_out;               // [64,32,32]

    char* ws = (char*)d_ws;                   // ws >= 512 MB (harness fills 512MB)
    _Float16* Wh     = (_Float16*)ws;                               // 64 MB
    _Float16* s_part = (_Float16*)(ws + (size_t)67108864);          // 16 MB
    float* v1        = (float*)(ws + (size_t)67108864 + 33554432);             // 256 KB
    float* v12       = (float*)(ws + (size_t)67108864 + 33554432 + 262144);    // 256 KB

    const int ublocks = NG * NRC2;   // 256 = 1 block/CU

    // iter 1: reads W fp32, persists Wh fp16; 1/32 applied as squash pre-scale
    upass<0><<<ublocks, 512, 0, stream>>>(x, W, Wh, nullptr, s_part);
    reduce_squash<<<512, 256, 0, stream>>>(s_part, 1.f / 32.f, v1, nullptr, nullptr);

    // iter 2: logits = u.v1 ; keep only v12 = v1 + v2
    upass<1><<<ublocks, 512, 0, stream>>>(x, nullptr, Wh, v1, s_part);
    reduce_squash<<<512, 256, 0, stream>>>(s_part, 1.f, nullptr, v1, v12);

    // iter 3: logits = u.(v1+v2) ; output v3
    upass<2><<<ublocks, 512, 0, stream>>>(x, nullptr, Wh, v12, s_part);
    reduce_squash<<<512, 256, 0, stream>>>(s_part, 1.f, out, nullptr, nullptr);
}